// Round 4
// baseline (852.311 us; speedup 1.0000x reference)
//
#include <hip/hip_runtime.h>
#include <math.h>

#define BB 8
#define SQL 2048
#define SKL 2048
#define DD 1024

typedef __attribute__((ext_vector_type(8))) short bf16x8;
typedef __attribute__((ext_vector_type(4))) float f32x4;
typedef __attribute__((ext_vector_type(16))) float f32x16;
typedef __attribute__((ext_vector_type(4))) unsigned short us4;
typedef unsigned short u16;

__device__ __forceinline__ u16 f2bf(float f) {
    unsigned u = __float_as_uint(f);
    u += 0x7fffu + ((u >> 16) & 1u);
    return (u16)(u >> 16);
}
__device__ __forceinline__ float bf2f(u16 h) {
    return __uint_as_float((unsigned)h << 16);
}

// ---- fp32 -> hi/lo bf16 planes ----
__global__ __launch_bounds__(256)
void split3(const float* __restrict__ in, u16* __restrict__ oh,
            u16* __restrict__ ol, long n4) {
    long i = (long)blockIdx.x * 256 + threadIdx.x;
    if (i >= n4) return;
    float4 v = ((const float4*)in)[i];
    us4 h, l;
    h.x = f2bf(v.x); l.x = f2bf(v.x - bf2f(h.x));
    h.y = f2bf(v.y); l.y = f2bf(v.y - bf2f(h.y));
    h.z = f2bf(v.z); l.z = f2bf(v.z - bf2f(h.z));
    h.w = f2bf(v.w); l.w = f2bf(v.w - bf2f(h.w));
    ((us4*)oh)[i] = h;
    ((us4*)ol)[i] = l;
}

// ---- W [K][N] fp32 -> WhT/WlT [N][K] bf16 planes (transpose + split) ----
__global__ __launch_bounds__(256)
void splitT3(const float* __restrict__ W, u16* __restrict__ WhT,
             u16* __restrict__ WlT) {
    __shared__ float t[32][33];
    const int n0 = blockIdx.x * 32, k0 = blockIdx.y * 32;
    const int tx = threadIdx.x & 31, ty = threadIdx.x >> 5;
#pragma unroll
    for (int r = 0; r < 32; r += 8)
        t[ty + r][tx] = W[(long)(k0 + ty + r) * DD + n0 + tx];
    __syncthreads();
#pragma unroll
    for (int r = 0; r < 32; r += 8) {
        float x = t[tx][ty + r];
        u16 h = f2bf(x);
        WhT[(long)(n0 + ty + r) * DD + k0 + tx] = h;
        WlT[(long)(n0 + ty + r) * DD + k0 + tx] = f2bf(x - bf2f(h));
    }
}

#define GLL(gp, lp) __builtin_amdgcn_global_load_lds( \
    (const __attribute__((address_space(1))) void*)(gp), \
    (__attribute__((address_space(3))) void*)(lp), 16, 0, 0)

#define MFMA32(a, b, c) __builtin_amdgcn_mfma_f32_32x32x16_bf16((a), (b), (c), 0, 0, 0)

// ---- 3-term split-bf16 NT GEMM: C = A·B^T ----
// 256x256 tile, 512 threads (8 waves: 2M x 4N), BK=32, double-buffered LDS
// (128 KB). Inner MFMA = 32x32x16 (2495 TF pipe vs 2075 for 16x16x32).
// Wave tile 128x64 = 4x2 blocks of 32x32, acc = 8 x f32x16.
// 4 sub-phases per K-tile (one A row-block each, 12 MFMA), B hoisted to
// registers once per tile, counted vmcnt folded into sub-phase barriers.
// mode 0: Cf = acc ; mode 3: Cf = acc + mask[col]
// mode 1: C1/C2 = split(acc + bias[col])
// mode 2: C1[col*ldc + row] = bf16(tanh(acc + bias[col]))  (transposed out)
__global__ __launch_bounds__(512, 2)
void gemm3(const u16* __restrict__ Ah, const u16* __restrict__ Al,
           const u16* __restrict__ Bh, const u16* __restrict__ Bl,
           int lda, int ldb, int K, long sA, long sB,
           const float* __restrict__ bias, const int* __restrict__ mask, int sM,
           float* __restrict__ Cf, u16* __restrict__ C1, u16* __restrict__ C2,
           long sC, int ldc, int mode)
{
    // Per buffer (32768 u16 = 64 KB):
    //   A packs p=0..3 at p*4096:   [2048 u16 hi | 2048 u16 lo], 64 rows x 32 k
    //   B packs p=0..3 at 16384 + p*4096, same structure.
    __shared__ u16 L[65536];   // 2 buffers = 128 KB

    const int z = blockIdx.z;
    const long zA = (long)z * sA, zB = (long)z * sB;
    const int tid = threadIdx.x, lane = tid & 63, wave = tid >> 6;
    const int wm = wave >> 2, wn = wave & 3;       // 2 x 4 wave grid
    const int l31 = lane & 31, lh = lane >> 5;
    const long row0 = (long)blockIdx.y * 256, col0 = (long)blockIdx.x * 256;

    // ---- staging map: one GLL = one 8KB pack (512 thr x 16B) ----
    const int pl = tid >> 8;
    const int c = tid & 255;
    const int srow = c >> 2;
    const int qg = (c & 3) ^ ((srow >> 1) & 3);
    const u16* sAp = (pl ? Al : Ah) + zA + qg * 8;
    const u16* sBp = (pl ? Bl : Bh) + zB + qg * 8;
    int ofA[4], ofB[4];
#pragma unroll
    for (int p = 0; p < 4; p++) {
        ofA[p] = (int)((row0 + p * 64 + srow) * (long)lda);
        ofB[p] = (int)((col0 + p * 64 + srow) * (long)ldb);
    }
    const int dst = tid * 8;   // u16 units, 16B per thread

#define STB(p, kk, bb) GLL(sBp + ofB[p] + (kk), L + (bb) + 16384 + (p) * 4096 + dst)
#define STA(p, kk, bb) GLL(sAp + ofA[p] + (kk), L + (bb) + (p) * 4096 + dst)

    // ---- fragment read offsets (swizzled), u16 units ----
    // 32x32x16 operand: lane holds row/col = lane&31, k = (lane>>5)*8 + e.
    // Logical k-quarter q = h*2 + (lane>>5); physical quarter = q ^ ((r>>1)&3).
    int aoff[8];   // [bi*2 + h]
#pragma unroll
    for (int bi = 0; bi < 4; bi++)
#pragma unroll
        for (int h = 0; h < 2; h++) {
            int r = wm * 128 + bi * 32 + l31;
            int q = h * 2 + lh;
            aoff[bi * 2 + h] = (r >> 6) * 4096 + (r & 63) * 32 + ((q ^ ((r >> 1) & 3)) * 8);
        }
    int boff[4];   // [bj*2 + h]
#pragma unroll
    for (int bj = 0; bj < 2; bj++)
#pragma unroll
        for (int h = 0; h < 2; h++) {
            int r = wn * 64 + bj * 32 + l31;
            int q = h * 2 + lh;
            boff[bj * 2 + h] = 16384 + (r >> 6) * 4096 + (r & 63) * 32 + ((q ^ ((r >> 1) & 3)) * 8);
        }

    f32x16 acc[4][2];
#pragma unroll
    for (int bi = 0; bi < 4; bi++)
#pragma unroll
        for (int bj = 0; bj < 2; bj++)
#pragma unroll
            for (int e = 0; e < 16; e++) acc[bi][bj][e] = 0.f;

#define BAR() do { __builtin_amdgcn_s_barrier(); \
                   __builtin_amdgcn_sched_barrier(0); } while (0)

    // sub-phase: A row-block bi (hi+lo, both k-halves), inject GLLs, 12 MFMAs.
#define SPX(bi, GLLCODE) do { \
    bf16x8 ah0 = *(const bf16x8*)(L + bo + aoff[(bi) * 2 + 0]); \
    bf16x8 al0 = *(const bf16x8*)(L + bo + aoff[(bi) * 2 + 0] + 2048); \
    bf16x8 ah1 = *(const bf16x8*)(L + bo + aoff[(bi) * 2 + 1]); \
    bf16x8 al1 = *(const bf16x8*)(L + bo + aoff[(bi) * 2 + 1] + 2048); \
    GLLCODE \
    __builtin_amdgcn_s_setprio(1); \
    _Pragma("unroll") \
    for (int bj = 0; bj < 2; bj++) { \
        f32x16 t_ = acc[bi][bj]; \
        t_ = MFMA32(ah0, yh[bj][0], t_); \
        t_ = MFMA32(ah0, yl[bj][0], t_); \
        t_ = MFMA32(al0, yh[bj][0], t_); \
        t_ = MFMA32(ah1, yh[bj][1], t_); \
        t_ = MFMA32(ah1, yl[bj][1], t_); \
        t_ = MFMA32(al1, yh[bj][1], t_); \
        acc[bi][bj] = t_; \
    } \
    __builtin_amdgcn_s_setprio(0); \
} while (0)

    // one K-tile: PF=1 -> prefetch tile t+1 (GLL issue order must stay
    // B0,B1,B2,B3,A0,A2,A1,A3 so vmcnt counts are uniform with prologue).
#define TILEB(PF) do { \
    bf16x8 yh[2][2], yl[2][2]; \
    _Pragma("unroll") \
    for (int bj = 0; bj < 2; bj++) \
        _Pragma("unroll") \
        for (int h = 0; h < 2; h++) { \
            yh[bj][h] = *(const bf16x8*)(L + bo + boff[bj * 2 + h]); \
            yl[bj][h] = *(const bf16x8*)(L + bo + boff[bj * 2 + h] + 2048); \
        } \
    /* sp0 */ \
    SPX(0, if (PF) { STB(0, kn, bn); STB(1, kn, bn); }); \
    BAR(); \
    /* sp1: after this, A1/A3(t) must be landed for sp2 reads */ \
    SPX(1, if (PF) { STB(2, kn, bn); STB(3, kn, bn); }); \
    if (PF) asm volatile("s_waitcnt vmcnt(4)" ::: "memory"); \
    else    asm volatile("s_waitcnt vmcnt(0)" ::: "memory"); \
    BAR(); \
    /* sp2 */ \
    SPX(2, if (PF) { STA(0, kn, bn); STA(2, kn, bn); }); \
    BAR(); \
    /* sp3: after this, B0-3/A0/A2(t+1) must be landed for sp0(t+1) */ \
    SPX(3, if (PF) { STA(1, kn, bn); STA(3, kn, bn); }); \
    if (PF) { asm volatile("s_waitcnt vmcnt(2)" ::: "memory"); BAR(); } \
} while (0)

    const int NT = K >> 5;
    // Prologue: tile 0 (order B0,B1,B2,B3,A0,A2,A1,A3), wait 6 oldest.
    STB(0, 0, 0); STB(1, 0, 0); STB(2, 0, 0); STB(3, 0, 0);
    STA(0, 0, 0); STA(2, 0, 0); STA(1, 0, 0); STA(3, 0, 0);
    asm volatile("s_waitcnt vmcnt(2)" ::: "memory");
    BAR();

    for (int t = 0; t < NT - 1; ++t) {
        const int bo = (t & 1) << 15;     // current buffer (u16 offset)
        const int bn = bo ^ 32768;        // next buffer
        const int kn = (t + 1) << 5;
        TILEB(1);
    }
    {   // peeled last tile: no prefetch
        const int bo = ((NT - 1) & 1) << 15;
        const int bn = bo ^ 32768; (void)bn;
        const int kn = 0; (void)kn;
        TILEB(0);
    }
#undef TILEB
#undef SPX
#undef BAR
#undef STA
#undef STB

    // ---- epilogue: 32x32 C/D layout: col = lane&31,
    //      row = (reg&3) + 8*(reg>>2) + 4*(lane>>5), reg = g*4+e ----
    const long zc = (long)z * sC;
#pragma unroll
    for (int bi = 0; bi < 4; bi++) {
#pragma unroll
        for (int bj = 0; bj < 2; bj++) {
            const long col = col0 + wn * 64 + bj * 32 + l31;
            const long rb0 = row0 + wm * 128 + bi * 32 + 4 * lh;
            if (mode == 0 || mode == 3) {
                const float madd = (mode == 3) ? (float)mask[(long)z * sM + col] : 0.f;
#pragma unroll
                for (int g = 0; g < 4; g++)
#pragma unroll
                    for (int e = 0; e < 4; e++)
                        Cf[zc + (rb0 + 8 * g + e) * (long)ldc + col] =
                            acc[bi][bj][g * 4 + e] + madd;
            } else if (mode == 1) {
                const float bv = bias[col];
#pragma unroll
                for (int g = 0; g < 4; g++)
#pragma unroll
                    for (int e = 0; e < 4; e++) {
                        float val = acc[bi][bj][g * 4 + e] + bv;
                        u16 h = f2bf(val);
                        const long idx = zc + (rb0 + 8 * g + e) * (long)ldc + col;
                        C1[idx] = h;
                        C2[idx] = f2bf(val - bf2f(h));
                    }
            } else {  // mode 2: transposed tanh bf16 (rows 4-consecutive per g)
                const float bv = bias[col];
#pragma unroll
                for (int g = 0; g < 4; g++) {
                    us4 o;
                    o.x = f2bf(tanhf(acc[bi][bj][g * 4 + 0] + bv));
                    o.y = f2bf(tanhf(acc[bi][bj][g * 4 + 1] + bv));
                    o.z = f2bf(tanhf(acc[bi][bj][g * 4 + 2] + bv));
                    o.w = f2bf(tanhf(acc[bi][bj][g * 4 + 3] + bv));
                    *(us4*)(C1 + zc + col * (long)ldc + rb0 + 8 * g) = o;
                }
            }
        }
    }
}

// ---- plain bf16 NT GEMM (1 MFMA per tile-chunk), fp32 out ----
__global__ __launch_bounds__(256, 2)
void gemm1(const u16* __restrict__ A, const u16* __restrict__ B,
           float* __restrict__ C, int lda, int ldb, int K,
           long sA, long sB, long sC, int ldc)
{
    __shared__ u16 As[4096], Bs[4096];

    const int z = blockIdx.z;
    const long zA = (long)z * sA, zB = (long)z * sB;
    const int tid = threadIdx.x, lane = tid & 63, wave = tid >> 6;
    const int wm = (wave & 1) * 64, wn = (wave >> 1) * 64;
    const int l15 = lane & 15, lq = lane >> 4;
    const long row0 = (long)blockIdx.y * 128, col0 = (long)blockIdx.x * 128;

    long offA[2], offB[2]; int lds[2];
#pragma unroll
    for (int it = 0; it < 2; it++) {
        int c = tid + it * 256, row = c >> 2;
        int qg = (c & 3) ^ ((row >> 1) & 3);
        offA[it] = (row0 + row) * (long)lda + qg * 8;
        offB[it] = (col0 + row) * (long)ldb + qg * 8;
        lds[it] = c * 8;
    }
    int aoff[4], boff[4];
#pragma unroll
    for (int i = 0; i < 4; i++) {
        int r = wm + i * 16 + l15;
        aoff[i] = r * 32 + ((lq ^ ((r >> 1) & 3)) * 8);
    }
#pragma unroll
    for (int j = 0; j < 4; j++) {
        int r = wn + j * 16 + l15;
        boff[j] = r * 32 + ((lq ^ ((r >> 1) & 3)) * 8);
    }

    f32x4 acc[4][4];
#pragma unroll
    for (int i = 0; i < 4; i++)
#pragma unroll
        for (int j = 0; j < 4; j++)
#pragma unroll
            for (int e = 0; e < 4; e++) acc[i][j][e] = 0.f;

    for (int k0 = 0; k0 < K; k0 += 32) {
#pragma unroll
        for (int it = 0; it < 2; it++) {
            GLL(A + zA + offA[it] + k0, As + lds[it]);
            GLL(B + zB + offB[it] + k0, Bs + lds[it]);
        }
        __syncthreads();
        bf16x8 af[4], bf[4];
#pragma unroll
        for (int i = 0; i < 4; i++) af[i] = *(const bf16x8*)(As + aoff[i]);
#pragma unroll
        for (int j = 0; j < 4; j++) bf[j] = *(const bf16x8*)(Bs + boff[j]);
#pragma unroll
        for (int i = 0; i < 4; i++)
#pragma unroll
            for (int j = 0; j < 4; j++)
                acc[i][j] = __builtin_amdgcn_mfma_f32_16x16x32_bf16(af[i], bf[j], acc[i][j], 0, 0, 0);
        __syncthreads();
    }

    const long zc = (long)z * sC;
#pragma unroll
    for (int i = 0; i < 4; i++)
#pragma unroll
        for (int j = 0; j < 4; j++) {
            const long col = col0 + wn + j * 16 + l15;
            const long rbase = row0 + wm + i * 16 + lq * 4;
#pragma unroll
            for (int r = 0; r < 4; r++)
                C[zc + (rbase + r) * (long)ldc + col] = acc[i][j][r];
        }
}

// ---- row softmax: fp32 row [2048] -> bf16 row in place (row stride 4096 u16) ----
__global__ __launch_bounds__(256)
void softmax_bf(float* __restrict__ S)
{
    float* p = S + (long)blockIdx.x * SKL;
    u16* po = (u16*)S + (long)blockIdx.x * 2 * SKL;
    const int tid = threadIdx.x;
    const int w = tid >> 6, lane = tid & 63;

    float4 v0 = *(float4*)(p + tid * 8);
    float4 v1 = *(float4*)(p + tid * 8 + 4);

    float m = fmaxf(fmaxf(fmaxf(v0.x, v0.y), fmaxf(v0.z, v0.w)),
                    fmaxf(fmaxf(v1.x, v1.y), fmaxf(v1.z, v1.w)));
#pragma unroll
    for (int off = 32; off; off >>= 1) m = fmaxf(m, __shfl_down(m, off));

    __shared__ float wm_[4], ws_[4];
    if (lane == 0) wm_[w] = m;
    __syncthreads();
    const float bm = fmaxf(fmaxf(wm_[0], wm_[1]), fmaxf(wm_[2], wm_[3]));

    v0.x = __expf(v0.x - bm); v0.y = __expf(v0.y - bm);
    v0.z = __expf(v0.z - bm); v0.w = __expf(v0.w - bm);
    v1.x = __expf(v1.x - bm); v1.y = __expf(v1.y - bm);
    v1.z = __expf(v1.z - bm); v1.w = __expf(v1.w - bm);

    float s = v0.x + v0.y + v0.z + v0.w + v1.x + v1.y + v1.z + v1.w;
#pragma unroll
    for (int off = 32; off; off >>= 1) s += __shfl_down(s, off);
    if (lane == 0) ws_[w] = s;
    __syncthreads();
    const float inv = 1.f / (ws_[0] + ws_[1] + ws_[2] + ws_[3]);

    us4 o0, o1;
    o0.x = f2bf(v0.x * inv); o0.y = f2bf(v0.y * inv);
    o0.z = f2bf(v0.z * inv); o0.w = f2bf(v0.w * inv);
    o1.x = f2bf(v1.x * inv); o1.y = f2bf(v1.y * inv);
    o1.z = f2bf(v1.z * inv); o1.w = f2bf(v1.w * inv);
    *(us4*)(po + tid * 8) = o0;
    *(us4*)(po + tid * 8 + 4) = o1;
}

extern "C" void kernel_launch(void* const* d_in, const int* in_sizes, int n_in,
                              void* d_out, int out_size, void* d_ws, size_t ws_size,
                              hipStream_t stream)
{
    const float* q  = (const float*)d_in[0];
    const float* k  = (const float*)d_in[1];
    const float* v  = (const float*)d_in[2];
    const int* mask = (const int*)d_in[3];
    const float* Wq = (const float*)d_in[4];
    const float* bq = (const float*)d_in[5];
    const float* Wk = (const float*)d_in[6];
    const float* bk = (const float*)d_in[7];
    const float* Wv = (const float*)d_in[8];
    const float* bv = (const float*)d_in[9];
    float* out = (float*)d_out;

    const long PZ = (long)SKL * DD;      // 2M elems per z per plane
    // ws layout (bytes): KpH 33.55M | KpL 33.55M | Vt 33.55M | S 134.2M = 234.9M
    u16*   KpH = (u16*)d_ws;
    u16*   KpL = KpH + BB * PZ;
    u16*   Vt  = KpL + BB * PZ;                 // [8][1024][2048]
    float* S   = (float*)(Vt + BB * PZ);        // [8][2048][2048] fp32
    // aliases inside S (dead before QK^T writes S):
    u16*   inH = (u16*)S;                       // [8][2048][1024]
    u16*   inL = inH + BB * PZ;
    u16*   WhT = inL + BB * PZ;                 // [1024][1024]
    u16*   WlT = WhT + (long)DD * DD;
    // Qp planes live in d_out (64 MB <= 67 MB); consumed by QK before PV writes out
    u16*   QpH = (u16*)d_out;
    u16*   QpL = QpH + BB * PZ;
    u16*   P   = (u16*)S;                       // softmax in place, row stride 4096

    const dim3 b256(256), b512(512);
    const long n4 = BB * PZ / 4;
    const dim3 gSplit((unsigned)(n4 / 256));
    const dim3 gW(32, 32);
    const dim3 gProj(DD / 256, SQL / 256, BB);   // (4, 8, 8)
    const dim3 gQK(SKL / 256, SQL / 256, BB);    // (8, 8, 8)
    const dim3 gPV(8, 16, BB);
    const dim3 gSm(BB * SQL);

    // --- Q projection -> Qp planes (d_out) ---
    split3<<<gSplit, b256, 0, stream>>>(q, inH, inL, n4);
    splitT3<<<gW, b256, 0, stream>>>(Wq, WhT, WlT);
    gemm3<<<gProj, b512, 0, stream>>>(inH, inL, WhT, WlT, DD, DD, DD, PZ, 0,
                                      bq, nullptr, 0, nullptr, QpH, QpL, PZ, DD, 1);
    // --- K projection -> Kp planes ---
    split3<<<gSplit, b256, 0, stream>>>(k, inH, inL, n4);
    splitT3<<<gW, b256, 0, stream>>>(Wk, WhT, WlT);
    gemm3<<<gProj, b512, 0, stream>>>(inH, inL, WhT, WlT, DD, DD, DD, PZ, 0,
                                      bk, nullptr, 0, nullptr, KpH, KpL, PZ, DD, 1);
    // --- V projection -> Vt transposed bf16 (+tanh) ---
    split3<<<gSplit, b256, 0, stream>>>(v, inH, inL, n4);
    splitT3<<<gW, b256, 0, stream>>>(Wv, WhT, WlT);
    gemm3<<<gProj, b512, 0, stream>>>(inH, inL, WhT, WlT, DD, DD, DD, PZ, 0,
                                      bv, nullptr, 0, nullptr, Vt, nullptr, PZ, SKL, 2);
    // --- QK^T + mask -> S fp32 (overwrites in/W aliases, both dead) ---
    gemm3<<<gQK, b512, 0, stream>>>(QpH, QpL, KpH, KpL, DD, DD, DD, PZ, PZ,
                                    nullptr, mask, SKL,
                                    S, nullptr, nullptr, (long)SQL * SKL, SKL, 3);
    // --- softmax rows -> bf16 in place ---
    softmax_bf<<<gSm, b256, 0, stream>>>(S);
    // --- PV (plain bf16) -> out ---
    gemm1<<<gPV, b256, 0, stream>>>(P, Vt, out, 2 * SKL, SKL, SKL,
                                    (long)SQL * 2 * SKL, PZ,
                                    (long)SQL * DD, DD);
}

// Round 5
// 840.032 us; speedup vs baseline: 1.0146x; 1.0146x over previous
//
#include <hip/hip_runtime.h>
#include <math.h>

#define BB 8
#define SQL 2048
#define SKL 2048
#define DD 1024

typedef __attribute__((ext_vector_type(8))) short bf16x8;
typedef __attribute__((ext_vector_type(4))) float f32x4;
typedef __attribute__((ext_vector_type(4))) unsigned short us4;
typedef unsigned short u16;

__device__ __forceinline__ u16 f2bf(float f) {
    unsigned u = __float_as_uint(f);
    u += 0x7fffu + ((u >> 16) & 1u);
    return (u16)(u >> 16);
}
__device__ __forceinline__ float bf2f(u16 h) {
    return __uint_as_float((unsigned)h << 16);
}

// ---- fp32 -> hi/lo bf16 planes ----
__global__ __launch_bounds__(256)
void split3(const float* __restrict__ in, u16* __restrict__ oh,
            u16* __restrict__ ol, long n4) {
    long i = (long)blockIdx.x * 256 + threadIdx.x;
    if (i >= n4) return;
    float4 v = ((const float4*)in)[i];
    us4 h, l;
    h.x = f2bf(v.x); l.x = f2bf(v.x - bf2f(h.x));
    h.y = f2bf(v.y); l.y = f2bf(v.y - bf2f(h.y));
    h.z = f2bf(v.z); l.z = f2bf(v.z - bf2f(h.z));
    h.w = f2bf(v.w); l.w = f2bf(v.w - bf2f(h.w));
    ((us4*)oh)[i] = h;
    ((us4*)ol)[i] = l;
}

// ---- W [K][N] fp32 -> WhT/WlT [N][K] bf16 planes (transpose + split) ----
__global__ __launch_bounds__(256)
void splitT3(const float* __restrict__ W, u16* __restrict__ WhT,
             u16* __restrict__ WlT) {
    __shared__ float t[32][33];
    const int n0 = blockIdx.x * 32, k0 = blockIdx.y * 32;
    const int tx = threadIdx.x & 31, ty = threadIdx.x >> 5;
#pragma unroll
    for (int r = 0; r < 32; r += 8)
        t[ty + r][tx] = W[(long)(k0 + ty + r) * DD + n0 + tx];
    __syncthreads();
#pragma unroll
    for (int r = 0; r < 32; r += 8) {
        float x = t[tx][ty + r];
        u16 h = f2bf(x);
        WhT[(long)(n0 + ty + r) * DD + k0 + tx] = h;
        WlT[(long)(n0 + ty + r) * DD + k0 + tx] = f2bf(x - bf2f(h));
    }
}

#define GLL(gp, lp) __builtin_amdgcn_global_load_lds( \
    (const __attribute__((address_space(1))) void*)(gp), \
    (__attribute__((address_space(3))) void*)(lp), 16, 0, 0)

// ---- 3-term split-bf16 NT GEMM: C = A·B^T ----
// 256x256 tile, 512 threads (8 waves: 2M x 4N), BK=32, double-buffered LDS
// (128 KB). 16x16x32 MFMA (conflict-free swizzle maps, verified r2).
// m201-style double-barrier sub-phases: {ds_read + GLL -> barrier ->
// lgkmcnt(0)+sched_barrier -> setprio+MFMA cluster -> barrier}.
// Counted vmcnt once per half-tile (never 0 in main loop).
// mode 0: Cf = acc ; mode 3: Cf = acc + mask[col]
// mode 1: C1/C2 = split(acc + bias[col])
// mode 2: C1[col*ldc + row] = bf16(tanh(acc + bias[col]))  (transposed out)
__global__ __launch_bounds__(512, 2)
void gemm3(const u16* __restrict__ Ah, const u16* __restrict__ Al,
           const u16* __restrict__ Bh, const u16* __restrict__ Bl,
           int lda, int ldb, int K, long sA, long sB,
           const float* __restrict__ bias, const int* __restrict__ mask, int sM,
           float* __restrict__ Cf, u16* __restrict__ C1, u16* __restrict__ C2,
           long sC, int ldc, int mode)
{
    // Per buffer (32768 u16 = 64 KB):
    //   A packs p=0..3 at p*4096:   [2048 u16 hi | 2048 u16 lo], 64 rows x 32 k
    //   B packs p=0..3 at 16384 + p*4096, same structure.
    __shared__ u16 L[65536];   // 2 buffers = 128 KB

    const int z = blockIdx.z;
    const long zA = (long)z * sA, zB = (long)z * sB;
    const int tid = threadIdx.x, lane = tid & 63, wave = tid >> 6;
    const int wm = wave >> 2, wn = wave & 3;       // 2 x 4 wave grid
    const int l15 = lane & 15, lq = lane >> 4;
    const long row0 = (long)blockIdx.y * 256, col0 = (long)blockIdx.x * 256;

    // ---- staging map: one GLL = one 8KB pack (512 thr x 16B) ----
    const int pl = tid >> 8;
    const int c = tid & 255;
    const int srow = c >> 2;
    const int qg = (c & 3) ^ ((srow >> 1) & 3);
    const u16* sAp = (pl ? Al : Ah) + zA + qg * 8;
    const u16* sBp = (pl ? Bl : Bh) + zB + qg * 8;
    int ofA[4], ofB[4];
#pragma unroll
    for (int p = 0; p < 4; p++) {
        ofA[p] = (int)((row0 + p * 64 + srow) * (long)lda);
        ofB[p] = (int)((col0 + p * 64 + srow) * (long)ldb);
    }
    const int dst = tid * 8;   // u16 units, 16B per thread

#define STB(p, kk, bb) GLL(sBp + ofB[p] + (kk), L + (bb) + 16384 + (p) * 4096 + dst)
#define STA(p, kk, bb) GLL(sAp + ofA[p] + (kk), L + (bb) + (p) * 4096 + dst)

    // ---- fragment read offsets (swizzled), u16 units ----
    int aoff[8], boff[4];
#pragma unroll
    for (int i = 0; i < 8; i++) {
        int r = wm * 128 + i * 16 + l15;
        aoff[i] = (r >> 6) * 4096 + (r & 63) * 32 + ((lq ^ ((r >> 1) & 3)) * 8);
    }
#pragma unroll
    for (int j = 0; j < 4; j++) {
        int r = wn * 64 + j * 16 + l15;
        boff[j] = 16384 + (r >> 6) * 4096 + (r & 63) * 32 + ((lq ^ ((r >> 1) & 3)) * 8);
    }

    f32x4 acc[8][4];
#pragma unroll
    for (int i = 0; i < 8; i++)
#pragma unroll
        for (int j = 0; j < 4; j++)
#pragma unroll
            for (int e = 0; e < 4; e++) acc[i][j][e] = 0.f;

#define BAR() do { __builtin_amdgcn_s_barrier(); \
                   __builtin_amdgcn_sched_barrier(0); } while (0)

    // sub-phase, m201 form: reads + GLL issue -> BARRIER -> lgkmcnt(0) ->
    // setprio(1) + 24 MFMA + setprio(0). Post-barrier added by TILEB.
#define SPX(iA, iB, GLLCODE) do { \
    bf16x8 xh0 = *(const bf16x8*)(L + bo + aoff[iA]); \
    bf16x8 xl0 = *(const bf16x8*)(L + bo + aoff[iA] + 2048); \
    bf16x8 xh1 = *(const bf16x8*)(L + bo + aoff[iB]); \
    bf16x8 xl1 = *(const bf16x8*)(L + bo + aoff[iB] + 2048); \
    GLLCODE \
    BAR(); \
    asm volatile("s_waitcnt lgkmcnt(0)" ::: "memory"); \
    __builtin_amdgcn_sched_barrier(0); \
    __builtin_amdgcn_s_setprio(1); \
    _Pragma("unroll") \
    for (int j = 0; j < 4; j++) { \
        f32x4 t0 = acc[iA][j]; \
        t0 = __builtin_amdgcn_mfma_f32_16x16x32_bf16(xh0, yh[j], t0, 0, 0, 0); \
        t0 = __builtin_amdgcn_mfma_f32_16x16x32_bf16(xh0, yl[j], t0, 0, 0, 0); \
        t0 = __builtin_amdgcn_mfma_f32_16x16x32_bf16(xl0, yh[j], t0, 0, 0, 0); \
        acc[iA][j] = t0; \
        f32x4 t1 = acc[iB][j]; \
        t1 = __builtin_amdgcn_mfma_f32_16x16x32_bf16(xh1, yh[j], t1, 0, 0, 0); \
        t1 = __builtin_amdgcn_mfma_f32_16x16x32_bf16(xh1, yl[j], t1, 0, 0, 0); \
        t1 = __builtin_amdgcn_mfma_f32_16x16x32_bf16(xl1, yh[j], t1, 0, 0, 0); \
        acc[iB][j] = t1; \
    } \
    __builtin_amdgcn_s_setprio(0); \
} while (0)

    // one K-tile: PF=1 -> prefetch tile t+1 (GLL issue order must stay
    // B0,B1,B2,B3,A0,A2,A1,A3 so vmcnt counts are uniform with prologue).
#define TILEB(PF) do { \
    bf16x8 yh[4], yl[4]; \
    _Pragma("unroll") \
    for (int j = 0; j < 4; j++) { \
        yh[j] = *(const bf16x8*)(L + bo + boff[j]); \
        yl[j] = *(const bf16x8*)(L + bo + boff[j] + 2048); \
    } \
    /* sp0: A rows [0,32) of wave-half */ \
    SPX(0, 1, if (PF) { STB(0, kn, bn); STB(1, kn, bn); }); \
    BAR(); \
    /* sp1 */ \
    SPX(2, 3, if (PF) { STB(2, kn, bn); STB(3, kn, bn); }); \
    /* A1/A3(t) must be landed before sp2's reads */ \
    if (PF) asm volatile("s_waitcnt vmcnt(4)" ::: "memory"); \
    else    asm volatile("s_waitcnt vmcnt(0)" ::: "memory"); \
    BAR(); \
    /* sp2 */ \
    SPX(4, 5, if (PF) { STA(0, kn, bn); STA(2, kn, bn); }); \
    BAR(); \
    /* sp3 */ \
    SPX(6, 7, if (PF) { STA(1, kn, bn); STA(3, kn, bn); }); \
    /* B0-3/A0/A2(t+1) must be landed before next tile's reads */ \
    if (PF) { asm volatile("s_waitcnt vmcnt(2)" ::: "memory"); } \
    BAR(); \
} while (0)

    const int NT = K >> 5;
    // Prologue: tile 0 (order B0,B1,B2,B3,A0,A2,A1,A3), wait 6 oldest.
    STB(0, 0, 0); STB(1, 0, 0); STB(2, 0, 0); STB(3, 0, 0);
    STA(0, 0, 0); STA(2, 0, 0); STA(1, 0, 0); STA(3, 0, 0);
    asm volatile("s_waitcnt vmcnt(2)" ::: "memory");
    BAR();

    for (int t = 0; t < NT - 1; ++t) {
        const int bo = (t & 1) << 15;     // current buffer (u16 offset)
        const int bn = bo ^ 32768;        // next buffer
        const int kn = (t + 1) << 5;
        TILEB(1);
    }
    {   // peeled last tile: no prefetch
        const int bo = ((NT - 1) & 1) << 15;
        const int bn = bo ^ 32768; (void)bn;
        const int kn = 0; (void)kn;
        TILEB(0);
    }
#undef TILEB
#undef SPX
#undef BAR
#undef STA
#undef STB

    const long zc = (long)z * sC;
#pragma unroll
    for (int i = 0; i < 8; i++) {
#pragma unroll
        for (int j = 0; j < 4; j++) {
            const long col = col0 + wn * 64 + j * 16 + l15;
            const long rbase = row0 + wm * 128 + i * 16 + lq * 4;
            if (mode == 0 || mode == 3) {
                const float madd = (mode == 3) ? (float)mask[(long)z * sM + col] : 0.f;
#pragma unroll
                for (int r = 0; r < 4; r++)
                    Cf[zc + (rbase + r) * (long)ldc + col] = acc[i][j][r] + madd;
            } else if (mode == 1) {
                const float bv = bias[col];
#pragma unroll
                for (int r = 0; r < 4; r++) {
                    float val = acc[i][j][r] + bv;
                    u16 h = f2bf(val);
                    C1[zc + (rbase + r) * (long)ldc + col] = h;
                    C2[zc + (rbase + r) * (long)ldc + col] = f2bf(val - bf2f(h));
                }
            } else {  // mode 2: transposed tanh bf16
                const float bv = bias[col];
                us4 o;
                o.x = f2bf(tanhf(acc[i][j][0] + bv));
                o.y = f2bf(tanhf(acc[i][j][1] + bv));
                o.z = f2bf(tanhf(acc[i][j][2] + bv));
                o.w = f2bf(tanhf(acc[i][j][3] + bv));
                *(us4*)(C1 + zc + col * (long)ldc + rbase) = o;
            }
        }
    }
}

// ---- plain bf16 NT GEMM (1 MFMA per tile-chunk), fp32 out ----
__global__ __launch_bounds__(256, 2)
void gemm1(const u16* __restrict__ A, const u16* __restrict__ B,
           float* __restrict__ C, int lda, int ldb, int K,
           long sA, long sB, long sC, int ldc)
{
    __shared__ u16 As[4096], Bs[4096];

    const int z = blockIdx.z;
    const long zA = (long)z * sA, zB = (long)z * sB;
    const int tid = threadIdx.x, lane = tid & 63, wave = tid >> 6;
    const int wm = (wave & 1) * 64, wn = (wave >> 1) * 64;
    const int l15 = lane & 15, lq = lane >> 4;
    const long row0 = (long)blockIdx.y * 128, col0 = (long)blockIdx.x * 128;

    long offA[2], offB[2]; int lds[2];
#pragma unroll
    for (int it = 0; it < 2; it++) {
        int c = tid + it * 256, row = c >> 2;
        int qg = (c & 3) ^ ((row >> 1) & 3);
        offA[it] = (row0 + row) * (long)lda + qg * 8;
        offB[it] = (col0 + row) * (long)ldb + qg * 8;
        lds[it] = c * 8;
    }
    int aoff[4], boff[4];
#pragma unroll
    for (int i = 0; i < 4; i++) {
        int r = wm + i * 16 + l15;
        aoff[i] = r * 32 + ((lq ^ ((r >> 1) & 3)) * 8);
    }
#pragma unroll
    for (int j = 0; j < 4; j++) {
        int r = wn + j * 16 + l15;
        boff[j] = r * 32 + ((lq ^ ((r >> 1) & 3)) * 8);
    }

    f32x4 acc[4][4];
#pragma unroll
    for (int i = 0; i < 4; i++)
#pragma unroll
        for (int j = 0; j < 4; j++)
#pragma unroll
            for (int e = 0; e < 4; e++) acc[i][j][e] = 0.f;

    for (int k0 = 0; k0 < K; k0 += 32) {
#pragma unroll
        for (int it = 0; it < 2; it++) {
            GLL(A + zA + offA[it] + k0, As + lds[it]);
            GLL(B + zB + offB[it] + k0, Bs + lds[it]);
        }
        __syncthreads();
        bf16x8 af[4], bf[4];
#pragma unroll
        for (int i = 0; i < 4; i++) af[i] = *(const bf16x8*)(As + aoff[i]);
#pragma unroll
        for (int j = 0; j < 4; j++) bf[j] = *(const bf16x8*)(Bs + boff[j]);
#pragma unroll
        for (int i = 0; i < 4; i++)
#pragma unroll
            for (int j = 0; j < 4; j++)
                acc[i][j] = __builtin_amdgcn_mfma_f32_16x16x32_bf16(af[i], bf[j], acc[i][j], 0, 0, 0);
        __syncthreads();
    }

    const long zc = (long)z * sC;
#pragma unroll
    for (int i = 0; i < 4; i++)
#pragma unroll
        for (int j = 0; j < 4; j++) {
            const long col = col0 + wn + j * 16 + l15;
            const long rbase = row0 + wm + i * 16 + lq * 4;
#pragma unroll
            for (int r = 0; r < 4; r++)
                C[zc + (rbase + r) * (long)ldc + col] = acc[i][j][r];
        }
}

// ---- row softmax: fp32 row [2048] -> bf16 row in place (row stride 4096 u16) ----
__global__ __launch_bounds__(256)
void softmax_bf(float* __restrict__ S)
{
    float* p = S + (long)blockIdx.x * SKL;
    u16* po = (u16*)S + (long)blockIdx.x * 2 * SKL;
    const int tid = threadIdx.x;
    const int w = tid >> 6, lane = tid & 63;

    float4 v0 = *(float4*)(p + tid * 8);
    float4 v1 = *(float4*)(p + tid * 8 + 4);

    float m = fmaxf(fmaxf(fmaxf(v0.x, v0.y), fmaxf(v0.z, v0.w)),
                    fmaxf(fmaxf(v1.x, v1.y), fmaxf(v1.z, v1.w)));
#pragma unroll
    for (int off = 32; off; off >>= 1) m = fmaxf(m, __shfl_down(m, off));

    __shared__ float wm_[4], ws_[4];
    if (lane == 0) wm_[w] = m;
    __syncthreads();
    const float bm = fmaxf(fmaxf(wm_[0], wm_[1]), fmaxf(wm_[2], wm_[3]));

    v0.x = __expf(v0.x - bm); v0.y = __expf(v0.y - bm);
    v0.z = __expf(v0.z - bm); v0.w = __expf(v0.w - bm);
    v1.x = __expf(v1.x - bm); v1.y = __expf(v1.y - bm);
    v1.z = __expf(v1.z - bm); v1.w = __expf(v1.w - bm);

    float s = v0.x + v0.y + v0.z + v0.w + v1.x + v1.y + v1.z + v1.w;
#pragma unroll
    for (int off = 32; off; off >>= 1) s += __shfl_down(s, off);
    if (lane == 0) ws_[w] = s;
    __syncthreads();
    const float inv = 1.f / (ws_[0] + ws_[1] + ws_[2] + ws_[3]);

    us4 o0, o1;
    o0.x = f2bf(v0.x * inv); o0.y = f2bf(v0.y * inv);
    o0.z = f2bf(v0.z * inv); o0.w = f2bf(v0.w * inv);
    o1.x = f2bf(v1.x * inv); o1.y = f2bf(v1.y * inv);
    o1.z = f2bf(v1.z * inv); o1.w = f2bf(v1.w * inv);
    *(us4*)(po + tid * 8) = o0;
    *(us4*)(po + tid * 8 + 4) = o1;
}

extern "C" void kernel_launch(void* const* d_in, const int* in_sizes, int n_in,
                              void* d_out, int out_size, void* d_ws, size_t ws_size,
                              hipStream_t stream)
{
    const float* q  = (const float*)d_in[0];
    const float* k  = (const float*)d_in[1];
    const float* v  = (const float*)d_in[2];
    const int* mask = (const int*)d_in[3];
    const float* Wq = (const float*)d_in[4];
    const float* bq = (const float*)d_in[5];
    const float* Wk = (const float*)d_in[6];
    const float* bk = (const float*)d_in[7];
    const float* Wv = (const float*)d_in[8];
    const float* bv = (const float*)d_in[9];
    float* out = (float*)d_out;

    const long PZ = (long)SKL * DD;      // 2M elems per z per plane
    // ws layout (bytes): KpH 33.55M | KpL 33.55M | Vt 33.55M | S 134.2M = 234.9M
    u16*   KpH = (u16*)d_ws;
    u16*   KpL = KpH + BB * PZ;
    u16*   Vt  = KpL + BB * PZ;                 // [8][1024][2048]
    float* S   = (float*)(Vt + BB * PZ);        // [8][2048][2048] fp32
    // aliases inside S (dead before QK^T writes S):
    u16*   inH = (u16*)S;                       // [8][2048][1024]
    u16*   inL = inH + BB * PZ;
    u16*   WhT = inL + BB * PZ;                 // [1024][1024]
    u16*   WlT = WhT + (long)DD * DD;
    // Qp planes live in d_out (64 MB <= 67 MB); consumed by QK before PV writes out
    u16*   QpH = (u16*)d_out;
    u16*   QpL = QpH + BB * PZ;
    u16*   P   = (u16*)S;                       // softmax in place, row stride 4096

    const dim3 b256(256), b512(512);
    const long n4 = BB * PZ / 4;
    const dim3 gSplit((unsigned)(n4 / 256));
    const dim3 gW(32, 32);
    const dim3 gProj(DD / 256, SQL / 256, BB);   // (4, 8, 8)
    const dim3 gQK(SKL / 256, SQL / 256, BB);    // (8, 8, 8)
    const dim3 gPV(8, 16, BB);
    const dim3 gSm(BB * SQL);

    // --- Q projection -> Qp planes (d_out) ---
    split3<<<gSplit, b256, 0, stream>>>(q, inH, inL, n4);
    splitT3<<<gW, b256, 0, stream>>>(Wq, WhT, WlT);
    gemm3<<<gProj, b512, 0, stream>>>(inH, inL, WhT, WlT, DD, DD, DD, PZ, 0,
                                      bq, nullptr, 0, nullptr, QpH, QpL, PZ, DD, 1);
    // --- K projection -> Kp planes ---
    split3<<<gSplit, b256, 0, stream>>>(k, inH, inL, n4);
    splitT3<<<gW, b256, 0, stream>>>(Wk, WhT, WlT);
    gemm3<<<gProj, b512, 0, stream>>>(inH, inL, WhT, WlT, DD, DD, DD, PZ, 0,
                                      bk, nullptr, 0, nullptr, KpH, KpL, PZ, DD, 1);
    // --- V projection -> Vt transposed bf16 (+tanh) ---
    split3<<<gSplit, b256, 0, stream>>>(v, inH, inL, n4);
    splitT3<<<gW, b256, 0, stream>>>(Wv, WhT, WlT);
    gemm3<<<gProj, b512, 0, stream>>>(inH, inL, WhT, WlT, DD, DD, DD, PZ, 0,
                                      bv, nullptr, 0, nullptr, Vt, nullptr, PZ, SKL, 2);
    // --- QK^T + mask -> S fp32 (overwrites in/W aliases, both dead) ---
    gemm3<<<gQK, b512, 0, stream>>>(QpH, QpL, KpH, KpL, DD, DD, DD, PZ, PZ,
                                    nullptr, mask, SKL,
                                    S, nullptr, nullptr, (long)SQL * SKL, SKL, 3);
    // --- softmax rows -> bf16 in place ---
    softmax_bf<<<gSm, b256, 0, stream>>>(S);
    // --- PV (plain bf16) -> out ---
    gemm1<<<gPV, b256, 0, stream>>>(P, Vt, out, 2 * SKL, SKL, SKL,
                                    (long)SQL * 2 * SKL, PZ,
                                    (long)SQL * DD, DD);
}

// Round 6
// 812.208 us; speedup vs baseline: 1.0494x; 1.0343x over previous
//
#include <hip/hip_runtime.h>
#include <math.h>

#define BB 8
#define SQL 2048
#define SKL 2048
#define DD 1024

typedef __attribute__((ext_vector_type(8))) short bf16x8;
typedef __attribute__((ext_vector_type(4))) float f32x4;
typedef __attribute__((ext_vector_type(4))) unsigned short us4;
typedef unsigned short u16;

__device__ __forceinline__ u16 f2bf(float f) {
    unsigned u = __float_as_uint(f);
    u += 0x7fffu + ((u >> 16) & 1u);
    return (u16)(u >> 16);
}
__device__ __forceinline__ float bf2f(u16 h) {
    return __uint_as_float((unsigned)h << 16);
}

// ---- fp32 -> hi/lo bf16 planes ----
__global__ __launch_bounds__(256)
void split3(const float* __restrict__ in, u16* __restrict__ oh,
            u16* __restrict__ ol, long n4) {
    long i = (long)blockIdx.x * 256 + threadIdx.x;
    if (i >= n4) return;
    float4 v = ((const float4*)in)[i];
    us4 h, l;
    h.x = f2bf(v.x); l.x = f2bf(v.x - bf2f(h.x));
    h.y = f2bf(v.y); l.y = f2bf(v.y - bf2f(h.y));
    h.z = f2bf(v.z); l.z = f2bf(v.z - bf2f(h.z));
    h.w = f2bf(v.w); l.w = f2bf(v.w - bf2f(h.w));
    ((us4*)oh)[i] = h;
    ((us4*)ol)[i] = l;
}

// ---- W [K][N] fp32 -> WhT/WlT [N][K] bf16 planes (transpose + split) ----
__global__ __launch_bounds__(256)
void splitT3(const float* __restrict__ W, u16* __restrict__ WhT,
             u16* __restrict__ WlT) {
    __shared__ float t[32][33];
    const int n0 = blockIdx.x * 32, k0 = blockIdx.y * 32;
    const int tx = threadIdx.x & 31, ty = threadIdx.x >> 5;
#pragma unroll
    for (int r = 0; r < 32; r += 8)
        t[ty + r][tx] = W[(long)(k0 + ty + r) * DD + n0 + tx];
    __syncthreads();
#pragma unroll
    for (int r = 0; r < 32; r += 8) {
        float x = t[tx][ty + r];
        u16 h = f2bf(x);
        WhT[(long)(n0 + ty + r) * DD + k0 + tx] = h;
        WlT[(long)(n0 + ty + r) * DD + k0 + tx] = f2bf(x - bf2f(h));
    }
}

#define GLL(gp, lp) __builtin_amdgcn_global_load_lds( \
    (const __attribute__((address_space(1))) void*)(gp), \
    (__attribute__((address_space(3))) void*)(lp), 16, 0, 0)

// ---- 3-term split-bf16 NT GEMM: C = A·B^T (round-2 verified version) ----
// 256x256 tile, 512 threads (8 waves: 2M x 4N), BK=32, double-buffered LDS
// (128 KB). 4 sub-phases per K-tile, B-fragments hoisted to registers once
// per tile, counted vmcnt folded into sub-phase barriers.
// mode 0: Cf = acc ; mode 3: Cf = acc + mask[col]
// mode 1: C1/C2 = split(acc + bias[col])
// mode 2: C1[col*ldc + row] = bf16(tanh(acc + bias[col]))  (transposed out)
__global__ __launch_bounds__(512, 2)
void gemm3(const u16* __restrict__ Ah, const u16* __restrict__ Al,
           const u16* __restrict__ Bh, const u16* __restrict__ Bl,
           int lda, int ldb, int K, long sA, long sB,
           const float* __restrict__ bias, const int* __restrict__ mask, int sM,
           float* __restrict__ Cf, u16* __restrict__ C1, u16* __restrict__ C2,
           long sC, int ldc, int mode)
{
    // Per buffer (32768 u16 = 64 KB):
    //   A packs p=0..3 at p*4096:   [2048 u16 hi | 2048 u16 lo], 64 rows x 32 k
    //   B packs p=0..3 at 16384 + p*4096, same structure.
    __shared__ u16 L[65536];   // 2 buffers = 128 KB

    const int z = blockIdx.z;
    const long zA = (long)z * sA, zB = (long)z * sB;
    const int tid = threadIdx.x, lane = tid & 63, wave = tid >> 6;
    const int wm = wave >> 2, wn = wave & 3;       // 2 x 4 wave grid
    const int l15 = lane & 15, lq = lane >> 4;
    const long row0 = (long)blockIdx.y * 256, col0 = (long)blockIdx.x * 256;

    // ---- staging map: one GLL = one 8KB pack (512 thr x 16B) ----
    const int pl = tid >> 8;
    const int c = tid & 255;
    const int srow = c >> 2;
    const int qg = (c & 3) ^ ((srow >> 1) & 3);
    const u16* sAp = (pl ? Al : Ah) + zA + qg * 8;
    const u16* sBp = (pl ? Bl : Bh) + zB + qg * 8;
    int ofA[4], ofB[4];
#pragma unroll
    for (int p = 0; p < 4; p++) {
        ofA[p] = (int)((row0 + p * 64 + srow) * (long)lda);
        ofB[p] = (int)((col0 + p * 64 + srow) * (long)ldb);
    }
    const int dst = tid * 8;   // u16 units, 16B per thread

#define STB(p, kk, bb) GLL(sBp + ofB[p] + (kk), L + (bb) + 16384 + (p) * 4096 + dst)
#define STA(p, kk, bb) GLL(sAp + ofA[p] + (kk), L + (bb) + (p) * 4096 + dst)

    // ---- fragment read offsets (swizzled), u16 units ----
    int aoff[8], boff[4];
#pragma unroll
    for (int i = 0; i < 8; i++) {
        int r = wm * 128 + i * 16 + l15;
        aoff[i] = (r >> 6) * 4096 + (r & 63) * 32 + ((lq ^ ((r >> 1) & 3)) * 8);
    }
#pragma unroll
    for (int j = 0; j < 4; j++) {
        int r = wn * 64 + j * 16 + l15;
        boff[j] = 16384 + (r >> 6) * 4096 + (r & 63) * 32 + ((lq ^ ((r >> 1) & 3)) * 8);
    }

    f32x4 acc[8][4];
#pragma unroll
    for (int i = 0; i < 8; i++)
#pragma unroll
        for (int j = 0; j < 4; j++)
#pragma unroll
            for (int e = 0; e < 4; e++) acc[i][j][e] = 0.f;

#define BAR() do { __builtin_amdgcn_s_barrier(); \
                   __builtin_amdgcn_sched_barrier(0); } while (0)

    // sub-phase: read A-fragments iA,iB (hi+lo), inject GLLs, 24 MFMAs.
#define SPX(iA, iB, GLLCODE) do { \
    bf16x8 xh0 = *(const bf16x8*)(L + bo + aoff[iA]); \
    bf16x8 xl0 = *(const bf16x8*)(L + bo + aoff[iA] + 2048); \
    bf16x8 xh1 = *(const bf16x8*)(L + bo + aoff[iB]); \
    bf16x8 xl1 = *(const bf16x8*)(L + bo + aoff[iB] + 2048); \
    GLLCODE \
    __builtin_amdgcn_s_setprio(1); \
    _Pragma("unroll") \
    for (int j = 0; j < 4; j++) { \
        f32x4 t0 = acc[iA][j]; \
        t0 = __builtin_amdgcn_mfma_f32_16x16x32_bf16(xh0, yh[j], t0, 0, 0, 0); \
        t0 = __builtin_amdgcn_mfma_f32_16x16x32_bf16(xh0, yl[j], t0, 0, 0, 0); \
        t0 = __builtin_amdgcn_mfma_f32_16x16x32_bf16(xl0, yh[j], t0, 0, 0, 0); \
        acc[iA][j] = t0; \
        f32x4 t1 = acc[iB][j]; \
        t1 = __builtin_amdgcn_mfma_f32_16x16x32_bf16(xh1, yh[j], t1, 0, 0, 0); \
        t1 = __builtin_amdgcn_mfma_f32_16x16x32_bf16(xh1, yl[j], t1, 0, 0, 0); \
        t1 = __builtin_amdgcn_mfma_f32_16x16x32_bf16(xl1, yh[j], t1, 0, 0, 0); \
        acc[iB][j] = t1; \
    } \
    __builtin_amdgcn_s_setprio(0); \
} while (0)

    // one K-tile: PF=1 -> prefetch tile t+1 (GLL issue order must stay
    // B0,B1,B2,B3,A0,A2,A1,A3 so vmcnt counts are uniform with prologue).
#define TILEB(PF) do { \
    bf16x8 yh[4], yl[4]; \
    _Pragma("unroll") \
    for (int j = 0; j < 4; j++) { \
        yh[j] = *(const bf16x8*)(L + bo + boff[j]); \
        yl[j] = *(const bf16x8*)(L + bo + boff[j] + 2048); \
    } \
    /* sp0 */ \
    SPX(0, 1, if (PF) { STB(0, kn, bn); STB(1, kn, bn); }); \
    BAR(); \
    /* sp1: after this, A1/A3(t) must be landed for sp2 reads */ \
    SPX(2, 3, if (PF) { STB(2, kn, bn); STB(3, kn, bn); }); \
    if (PF) asm volatile("s_waitcnt vmcnt(4)" ::: "memory"); \
    else    asm volatile("s_waitcnt vmcnt(0)" ::: "memory"); \
    BAR(); \
    /* sp2 */ \
    SPX(4, 5, if (PF) { STA(0, kn, bn); STA(2, kn, bn); }); \
    BAR(); \
    /* sp3: after this, B0-3/A0/A2(t+1) must be landed for sp0(t+1) */ \
    SPX(6, 7, if (PF) { STA(1, kn, bn); STA(3, kn, bn); }); \
    if (PF) { asm volatile("s_waitcnt vmcnt(2)" ::: "memory"); BAR(); } \
} while (0)

    const int NT = K >> 5;
    // Prologue: tile 0 (order B0,B1,B2,B3,A0,A2,A1,A3), wait 6 oldest.
    STB(0, 0, 0); STB(1, 0, 0); STB(2, 0, 0); STB(3, 0, 0);
    STA(0, 0, 0); STA(2, 0, 0); STA(1, 0, 0); STA(3, 0, 0);
    asm volatile("s_waitcnt vmcnt(2)" ::: "memory");
    BAR();

    for (int t = 0; t < NT - 1; ++t) {
        const int bo = (t & 1) << 15;     // current buffer (u16 offset)
        const int bn = bo ^ 32768;        // next buffer
        const int kn = (t + 1) << 5;
        TILEB(1);
    }
    {   // peeled last tile: no prefetch
        const int bo = ((NT - 1) & 1) << 15;
        const int bn = bo ^ 32768; (void)bn;
        const int kn = 0; (void)kn;
        TILEB(0);
    }
#undef TILEB
#undef SPX
#undef STA
#undef STB

    const long zc = (long)z * sC;
#pragma unroll
    for (int i = 0; i < 8; i++) {
#pragma unroll
        for (int j = 0; j < 4; j++) {
            const long col = col0 + wn * 64 + j * 16 + l15;
            const long rbase = row0 + wm * 128 + i * 16 + lq * 4;
            if (mode == 0 || mode == 3) {
                const float madd = (mode == 3) ? (float)mask[(long)z * sM + col] : 0.f;
#pragma unroll
                for (int r = 0; r < 4; r++)
                    Cf[zc + (rbase + r) * (long)ldc + col] = acc[i][j][r] + madd;
            } else if (mode == 1) {
                const float bv = bias[col];
#pragma unroll
                for (int r = 0; r < 4; r++) {
                    float val = acc[i][j][r] + bv;
                    u16 h = f2bf(val);
                    C1[zc + (rbase + r) * (long)ldc + col] = h;
                    C2[zc + (rbase + r) * (long)ldc + col] = f2bf(val - bf2f(h));
                }
            } else {  // mode 2: transposed tanh bf16
                const float bv = bias[col];
                us4 o;
                o.x = f2bf(tanhf(acc[i][j][0] + bv));
                o.y = f2bf(tanhf(acc[i][j][1] + bv));
                o.z = f2bf(tanhf(acc[i][j][2] + bv));
                o.w = f2bf(tanhf(acc[i][j][3] + bv));
                *(us4*)(C1 + zc + col * (long)ldc + rbase) = o;
            }
        }
    }
#undef BAR
}

// ---- plain bf16 NT GEMM, 256x256 tile (round-2 skeleton, single plane) ----
// 512 threads (8 waves: 2M x 4N), BK=32, double-buffered 64 KB LDS.
// Per buffer (16384 u16): A [0,8192) = 256 rows x 32 k; B [8192,16384).
// 4 GLL per tile (8 KB each), issued at tile top (issue->use = full tile).
__global__ __launch_bounds__(512, 2)
void gemm1w(const u16* __restrict__ A, const u16* __restrict__ B,
            float* __restrict__ C, int lda, int ldb, int K,
            long sA, long sB, long sC, int ldc)
{
    __shared__ u16 L[32768];   // 2 buffers = 64 KB

    const int z = blockIdx.z;
    const long zA = (long)z * sA, zB = (long)z * sB;
    const int tid = threadIdx.x, lane = tid & 63, wave = tid >> 6;
    const int wm = wave >> 2, wn = wave & 3;       // 2 x 4 wave grid
    const int l15 = lane & 15, lq = lane >> 4;
    const long row0 = (long)blockIdx.y * 256, col0 = (long)blockIdx.x * 256;

    // staging: one GLL = 8 KB = 128 rows x 32 k; pack p adds 128 rows.
    const int srow = tid >> 2;                      // 0..127
    const int qg = (tid & 3) ^ ((srow >> 1) & 3);
    int ofA[2], ofB[2];
#pragma unroll
    for (int p = 0; p < 2; p++) {
        ofA[p] = (int)((row0 + p * 128 + srow) * (long)lda) + qg * 8;
        ofB[p] = (int)((col0 + p * 128 + srow) * (long)ldb) + qg * 8;
    }
    const int dst = tid * 8;

#define STA1(p, kk, bb) GLL(A + zA + ofA[p] + (kk), L + (bb) + (p) * 4096 + dst)
#define STB1(p, kk, bb) GLL(B + zB + ofB[p] + (kk), L + (bb) + 8192 + (p) * 4096 + dst)

    int aoff[8], boff[4];
#pragma unroll
    for (int i = 0; i < 8; i++) {
        int r = wm * 128 + i * 16 + l15;
        aoff[i] = r * 32 + ((lq ^ ((r >> 1) & 3)) * 8);
    }
#pragma unroll
    for (int j = 0; j < 4; j++) {
        int r = wn * 64 + j * 16 + l15;
        boff[j] = 8192 + r * 32 + ((lq ^ ((r >> 1) & 3)) * 8);
    }

    f32x4 acc[8][4];
#pragma unroll
    for (int i = 0; i < 8; i++)
#pragma unroll
        for (int j = 0; j < 4; j++)
#pragma unroll
            for (int e = 0; e < 4; e++) acc[i][j][e] = 0.f;

#define BAR() do { __builtin_amdgcn_s_barrier(); \
                   __builtin_amdgcn_sched_barrier(0); } while (0)

#define HALF1(i0) do { \
    bf16x8 a0 = *(const bf16x8*)(L + bo + aoff[(i0) + 0]); \
    bf16x8 a1 = *(const bf16x8*)(L + bo + aoff[(i0) + 1]); \
    bf16x8 a2 = *(const bf16x8*)(L + bo + aoff[(i0) + 2]); \
    bf16x8 a3 = *(const bf16x8*)(L + bo + aoff[(i0) + 3]); \
    __builtin_amdgcn_s_setprio(1); \
    _Pragma("unroll") \
    for (int j = 0; j < 4; j++) { \
        acc[(i0)+0][j] = __builtin_amdgcn_mfma_f32_16x16x32_bf16(a0, yh[j], acc[(i0)+0][j], 0, 0, 0); \
        acc[(i0)+1][j] = __builtin_amdgcn_mfma_f32_16x16x32_bf16(a1, yh[j], acc[(i0)+1][j], 0, 0, 0); \
        acc[(i0)+2][j] = __builtin_amdgcn_mfma_f32_16x16x32_bf16(a2, yh[j], acc[(i0)+2][j], 0, 0, 0); \
        acc[(i0)+3][j] = __builtin_amdgcn_mfma_f32_16x16x32_bf16(a3, yh[j], acc[(i0)+3][j], 0, 0, 0); \
    } \
    __builtin_amdgcn_s_setprio(0); \
} while (0)

#define TILE1(PF) do { \
    if (PF) { STB1(0, kn, bn); STB1(1, kn, bn); STA1(0, kn, bn); STA1(1, kn, bn); } \
    __builtin_amdgcn_sched_barrier(0); \
    bf16x8 yh[4]; \
    _Pragma("unroll") \
    for (int j = 0; j < 4; j++) yh[j] = *(const bf16x8*)(L + bo + boff[j]); \
    HALF1(0); \
    BAR(); \
    HALF1(4); \
    asm volatile("s_waitcnt vmcnt(0)" ::: "memory"); \
    BAR(); \
} while (0)

    const int NT = K >> 5;
    STB1(0, 0, 0); STB1(1, 0, 0); STA1(0, 0, 0); STA1(1, 0, 0);
    asm volatile("s_waitcnt vmcnt(0)" ::: "memory");
    BAR();

    for (int t = 0; t < NT - 1; ++t) {
        const int bo = (t & 1) << 14;
        const int bn = bo ^ 16384;
        const int kn = (t + 1) << 5;
        TILE1(1);
    }
    {
        const int bo = ((NT - 1) & 1) << 14;
        const int bn = bo ^ 16384; (void)bn;
        const int kn = 0; (void)kn;
        TILE1(0);
    }
#undef TILE1
#undef HALF1
#undef BAR
#undef STA1
#undef STB1

    const long zc = (long)z * sC;
#pragma unroll
    for (int i = 0; i < 8; i++)
#pragma unroll
        for (int j = 0; j < 4; j++) {
            const long col = col0 + wn * 64 + j * 16 + l15;
            const long rbase = row0 + wm * 128 + i * 16 + lq * 4;
#pragma unroll
            for (int r = 0; r < 4; r++)
                C[zc + (rbase + r) * (long)ldc + col] = acc[i][j][r];
        }
}

// ---- row softmax: one WAVE per row, no LDS, no barriers ----
// fp32 row [2048] -> bf16 row in place (row stride 4096 u16)
__global__ __launch_bounds__(512)
void softmax_bf(float* __restrict__ S)
{
    const long row = (long)blockIdx.x * 8 + (threadIdx.x >> 6);
    float* p = S + row * SKL;
    u16* po = (u16*)S + row * 2 * SKL;
    const int lane = threadIdx.x & 63;

    float4 v[8];
#pragma unroll
    for (int i = 0; i < 8; i++) v[i] = ((const float4*)p)[lane + 64 * i];

    float m = -1e30f;
#pragma unroll
    for (int i = 0; i < 8; i++)
        m = fmaxf(m, fmaxf(fmaxf(v[i].x, v[i].y), fmaxf(v[i].z, v[i].w)));
#pragma unroll
    for (int off = 32; off; off >>= 1) m = fmaxf(m, __shfl_xor(m, off));

    float s = 0.f;
#pragma unroll
    for (int i = 0; i < 8; i++) {
        v[i].x = __expf(v[i].x - m); v[i].y = __expf(v[i].y - m);
        v[i].z = __expf(v[i].z - m); v[i].w = __expf(v[i].w - m);
        s += v[i].x + v[i].y + v[i].z + v[i].w;
    }
#pragma unroll
    for (int off = 32; off; off >>= 1) s += __shfl_xor(s, off);
    const float inv = 1.f / s;

#pragma unroll
    for (int i = 0; i < 8; i++) {
        us4 o;
        o.x = f2bf(v[i].x * inv); o.y = f2bf(v[i].y * inv);
        o.z = f2bf(v[i].z * inv); o.w = f2bf(v[i].w * inv);
        ((us4*)po)[lane + 64 * i] = o;
    }
}

extern "C" void kernel_launch(void* const* d_in, const int* in_sizes, int n_in,
                              void* d_out, int out_size, void* d_ws, size_t ws_size,
                              hipStream_t stream)
{
    const float* q  = (const float*)d_in[0];
    const float* k  = (const float*)d_in[1];
    const float* v  = (const float*)d_in[2];
    const int* mask = (const int*)d_in[3];
    const float* Wq = (const float*)d_in[4];
    const float* bq = (const float*)d_in[5];
    const float* Wk = (const float*)d_in[6];
    const float* bk = (const float*)d_in[7];
    const float* Wv = (const float*)d_in[8];
    const float* bv = (const float*)d_in[9];
    float* out = (float*)d_out;

    const long PZ = (long)SKL * DD;      // 2M elems per z per plane
    // ws layout (bytes): KpH 33.55M | KpL 33.55M | Vt 33.55M | S 134.2M = 234.9M
    u16*   KpH = (u16*)d_ws;
    u16*   KpL = KpH + BB * PZ;
    u16*   Vt  = KpL + BB * PZ;                 // [8][1024][2048]
    float* S   = (float*)(Vt + BB * PZ);        // [8][2048][2048] fp32
    // aliases inside S (dead before QK^T writes S):
    u16*   inH = (u16*)S;                       // [8][2048][1024]
    u16*   inL = inH + BB * PZ;
    u16*   WhT = inL + BB * PZ;                 // [1024][1024]
    u16*   WlT = WhT + (long)DD * DD;
    // Qp planes live in d_out (64 MB <= 67 MB); consumed by QK before PV writes out
    u16*   QpH = (u16*)d_out;
    u16*   QpL = QpH + BB * PZ;
    u16*   P   = (u16*)S;                       // softmax in place, row stride 4096

    const dim3 b256(256), b512(512);
    const long n4 = BB * PZ / 4;
    const dim3 gSplit((unsigned)(n4 / 256));
    const dim3 gW(32, 32);
    const dim3 gProj(DD / 256, SQL / 256, BB);   // (4, 8, 8)
    const dim3 gQK(SKL / 256, SQL / 256, BB);    // (8, 8, 8)
    const dim3 gPV(DD / 256, SQL / 256, BB);     // (4, 8, 8)
    const dim3 gSm(BB * SQL / 8);                // one wave per row, 8 rows/block

    // --- Q projection -> Qp planes (d_out) ---
    split3<<<gSplit, b256, 0, stream>>>(q, inH, inL, n4);
    splitT3<<<gW, b256, 0, stream>>>(Wq, WhT, WlT);
    gemm3<<<gProj, b512, 0, stream>>>(inH, inL, WhT, WlT, DD, DD, DD, PZ, 0,
                                      bq, nullptr, 0, nullptr, QpH, QpL, PZ, DD, 1);
    // --- K projection -> Kp planes ---
    split3<<<gSplit, b256, 0, stream>>>(k, inH, inL, n4);
    splitT3<<<gW, b256, 0, stream>>>(Wk, WhT, WlT);
    gemm3<<<gProj, b512, 0, stream>>>(inH, inL, WhT, WlT, DD, DD, DD, PZ, 0,
                                      bk, nullptr, 0, nullptr, KpH, KpL, PZ, DD, 1);
    // --- V projection -> Vt transposed bf16 (+tanh) ---
    split3<<<gSplit, b256, 0, stream>>>(v, inH, inL, n4);
    splitT3<<<gW, b256, 0, stream>>>(Wv, WhT, WlT);
    gemm3<<<gProj, b512, 0, stream>>>(inH, inL, WhT, WlT, DD, DD, DD, PZ, 0,
                                      bv, nullptr, 0, nullptr, Vt, nullptr, PZ, SKL, 2);
    // --- QK^T + mask -> S fp32 (overwrites in/W aliases, both dead) ---
    gemm3<<<gQK, b512, 0, stream>>>(QpH, QpL, KpH, KpL, DD, DD, DD, PZ, PZ,
                                    nullptr, mask, SKL,
                                    S, nullptr, nullptr, (long)SQL * SKL, SKL, 3);
    // --- softmax rows -> bf16 in place (wave-per-row) ---
    softmax_bf<<<gSm, b512, 0, stream>>>(S);
    // --- PV (plain bf16, 256^2 pipelined) -> out ---
    gemm1w<<<gPV, b512, 0, stream>>>(P, Vt, out, 2 * SKL, SKL, SKL,
                                     (long)SQL * 2 * SKL, PZ,
                                     (long)SQL * DD, DD);
}